// Round 11
// baseline (170.984 us; speedup 1.0000x reference)
//
#include <hip/hip_runtime.h>
#include <math.h>

#define Bn 4
#define Tn 4096
#define En 256
#define An 64
#define PLS 72    // epilogue LDS row stride in shorts (144 B, 16B-aligned)
#define WLS 264   // W LDS row stride in shorts (528 B, 16B-aligned)

typedef __attribute__((ext_vector_type(8))) short short8;
typedef __attribute__((ext_vector_type(8))) __bf16 bf16x8;
typedef __attribute__((ext_vector_type(4))) float f32x4;
typedef __attribute__((ext_vector_type(4))) short short4v;
typedef __attribute__((ext_vector_type(4))) _Float16 f16x4;
typedef __attribute__((ext_vector_type(2))) unsigned int uint2v;

__device__ __forceinline__ f32x4 mfma16(short8 a, short8 b, f32x4 c) {
    return __builtin_amdgcn_mfma_f32_16x16x32_bf16(
        __builtin_bit_cast(bf16x8, a), __builtin_bit_cast(bf16x8, b), c, 0, 0, 0);
}
__device__ __forceinline__ f32x4 mfma16h(f16x4 a, f16x4 b, f32x4 c) {
    return __builtin_amdgcn_mfma_f32_16x16x16f16(a, b, c, 0, 0, 0);
}
__device__ __forceinline__ unsigned short f2bf(float x) {   // RNE fp32->bf16
    unsigned int u = __builtin_bit_cast(unsigned int, x);
    u += 0x7fffu + ((u >> 16) & 1u);
    return (unsigned short)(u >> 16);
}
__device__ __forceinline__ float bf2f(unsigned short h) {
    return __builtin_bit_cast(float, (unsigned int)h << 16);
}
__device__ __forceinline__ unsigned int packbf2(float lo, float hi) {
    return (unsigned int)f2bf(lo) | ((unsigned int)f2bf(hi) << 16);
}
__device__ __forceinline__ unsigned short f2h(float x) {
    _Float16 h = (_Float16)x;
    return __builtin_bit_cast(unsigned short, h);
}

// ---------------------------------------------------------------------------
// Kernel 1: QKV projection, in-kernel W staging, LDS-transposed coalesced
// stores.  grid 512: jh=bid&1 (column half), rb=bid>>1 (64-row block).
// Outputs: q bf16 [b][t][a] pre-scaled 0.125*log2e, k bf16 [b][t][a],
//          v_t **f16** [b][a][t] (A-operand for the K=16 PV MFMA).
// ---------------------------------------------------------------------------
__global__ __launch_bounds__(256, 2) void proj_kernel(
    const float* __restrict__ emb,
    const float* __restrict__ Wq, const float* __restrict__ Wk, const float* __restrict__ Wv,
    const float* __restrict__ bq, const float* __restrict__ bk, const float* __restrict__ bv,
    unsigned short* __restrict__ qg, unsigned short* __restrict__ kg,
    unsigned short* __restrict__ v_t)
{
    const int bid  = blockIdx.x;
    const int tid  = threadIdx.x;
    const int wave = tid >> 6, lane = tid & 63, quad = lane >> 4, l15 = lane & 15;
    const int jh   = bid & 1;
    const int rb   = bid >> 1;
    const int row0  = rb * 64;            // flat row in [0, B*T)
    const int b     = row0 >> 12;
    const int trow0 = row0 & 4095;

    __shared__ unsigned short Wl[96 * WLS];   // W^T staging [lr][e]
    __shared__ unsigned short vtr[64 * PLS];  // tile transpose buffer

    {   // stage 96 W columns, transposed+bf16
        const float* __restrict__ srcA = jh ? Wv : Wq;
        const int lrbA = jh ? 32 : 0;
#pragma unroll
        for (int it = 0; it < 16; it++) {
            const int idx = it * 256 + tid;
            const int e   = idx >> 4;
            const int c4  = (idx & 15) * 4;
            float4 w = *(const float4*)&srcA[(size_t)e * An + c4];
            Wl[(lrbA + c4 + 0) * WLS + e] = f2bf(w.x);
            Wl[(lrbA + c4 + 1) * WLS + e] = f2bf(w.y);
            Wl[(lrbA + c4 + 2) * WLS + e] = f2bf(w.z);
            Wl[(lrbA + c4 + 3) * WLS + e] = f2bf(w.w);
        }
        const int coloff = jh ? 32 : 0;
        const int lrbB   = jh ? 0 : 64;
#pragma unroll
        for (int it = 0; it < 8; it++) {
            const int idx = it * 256 + tid;
            const int e   = idx >> 3;
            const int c4  = (idx & 7) * 4;
            float4 w = *(const float4*)&Wk[(size_t)e * An + coloff + c4];
            Wl[(lrbB + c4 + 0) * WLS + e] = f2bf(w.x);
            Wl[(lrbB + c4 + 1) * WLS + e] = f2bf(w.y);
            Wl[(lrbB + c4 + 2) * WLS + e] = f2bf(w.z);
            Wl[(lrbB + c4 + 3) * WLS + e] = f2bf(w.w);
        }
    }

    // A-fragments: emb rows fp32 -> bf16
    short8 A[8];
    {
        const float* erow = emb + (size_t)(row0 + wave * 16 + l15) * En;
#pragma unroll
        for (int c = 0; c < 8; c++) {
            const float* pp = erow + c * 32 + quad * 8;
            float4 f0 = *(const float4*)pp;
            float4 f1 = *(const float4*)(pp + 4);
            A[c] = (short8){(short)f2bf(f0.x), (short)f2bf(f0.y), (short)f2bf(f0.z), (short)f2bf(f0.w),
                            (short)f2bf(f1.x), (short)f2bf(f1.y), (short)f2bf(f1.z), (short)f2bf(f1.w)};
        }
    }
    __syncthreads();

    f32x4 acc[6];
#pragma unroll
    for (int x = 0; x < 6; x++) acc[x] = (f32x4){0.f, 0.f, 0.f, 0.f};

#pragma unroll
    for (int x = 0; x < 6; x++) {
        const unsigned short* wrow = &Wl[(x * 16 + l15) * WLS];
#pragma unroll
        for (int c = 0; c < 8; c++)
            acc[x] = mfma16(A[c], *(const short8*)(wrow + c * 32 + quad * 8), acc[x]);
    }

    const float QS = 0.125f * 1.4426950408889634f;   // 1/sqrt(A) * log2(e)
    const int row_l = wave * 16 + quad * 4;          // C/D: row=quad*4+reg, col=l15

    if (jh == 0) {
        // q full tile (nt 0..3)
        __syncthreads();
#pragma unroll
        for (int x = 0; x < 4; x++) {
            const int al = x * 16 + l15;
            const float bsv = bq[al];
#pragma unroll
            for (int rg = 0; rg < 4; rg++)
                vtr[(row_l + rg) * PLS + al] = f2bf((acc[x][rg] + bsv) * QS);
        }
        __syncthreads();
        if (tid < 128) {
            const int row = tid >> 1, cg = (tid & 1) * 32;
            unsigned short* dst = qg + (size_t)(row0 + row) * An + cg;
            *(short8*)dst        = *(const short8*)&vtr[row * PLS + cg];
            *(short8*)(dst + 8)  = *(const short8*)&vtr[row * PLS + cg + 8];
            *(short8*)(dst + 16) = *(const short8*)&vtr[row * PLS + cg + 16];
            *(short8*)(dst + 24) = *(const short8*)&vtr[row * PLS + cg + 24];
        }
        // k cols 0..31 (nt 4,5)
        __syncthreads();
#pragma unroll
        for (int x = 4; x < 6; x++) {
            const int al = (x - 4) * 16 + l15;
            const float bsv = bk[al];
#pragma unroll
            for (int rg = 0; rg < 4; rg++)
                vtr[(row_l + rg) * PLS + al] = f2bf(acc[x][rg] + bsv);
        }
        __syncthreads();
        if (tid < 64) {
            const int row = tid;
            unsigned short* dst = kg + (size_t)(row0 + row) * An;
            *(short8*)dst        = *(const short8*)&vtr[row * PLS];
            *(short8*)(dst + 8)  = *(const short8*)&vtr[row * PLS + 8];
            *(short8*)(dst + 16) = *(const short8*)&vtr[row * PLS + 16];
            *(short8*)(dst + 24) = *(const short8*)&vtr[row * PLS + 24];
        }
    } else {
        // k cols 32..63 (nt 6,7)
        __syncthreads();
#pragma unroll
        for (int x = 0; x < 2; x++) {
            const int al = (2 + x) * 16 + l15;
            const float bsv = bk[al];
#pragma unroll
            for (int rg = 0; rg < 4; rg++)
                vtr[(row_l + rg) * PLS + al] = f2bf(acc[x][rg] + bsv);
        }
        __syncthreads();
        if (tid < 64) {
            const int row = tid;
            unsigned short* dst = kg + (size_t)(row0 + row) * An + 32;
            *(short8*)dst        = *(const short8*)&vtr[row * PLS + 32];
            *(short8*)(dst + 8)  = *(const short8*)&vtr[row * PLS + 40];
            *(short8*)(dst + 16) = *(const short8*)&vtr[row * PLS + 48];
            *(short8*)(dst + 24) = *(const short8*)&vtr[row * PLS + 56];
        }
        // v full tile (nt 8..11), TRANSPOSED [a][row], stored as f16
        __syncthreads();
#pragma unroll
        for (int x = 2; x < 6; x++) {
            const int al = (x - 2) * 16 + l15;
            const float bsv = bv[al];
#pragma unroll
            for (int rg = 0; rg < 4; rg++)
                vtr[al * PLS + row_l + rg] = f2h(acc[x][rg] + bsv);
        }
        __syncthreads();
        {
            const int a  = tid >> 2;
            const int tg = (tid & 3) * 16;
            unsigned short* dst = v_t + (size_t)(b * 64 + a) * Tn + trow0 + tg;
            *(short8*)dst       = *(const short8*)&vtr[a * PLS + tg];
            *(short8*)(dst + 8) = *(const short8*)&vtr[a * PLS + tg + 8];
        }
    }
}

// ---------------------------------------------------------------------------
// Kernel 2: flash attention, 32 q-rows/wave, ZERO-LDS K-loop:
//  - QK^T: 16x16x32 bf16 MFMA, S^T[kv][qrow] in C/D layout
//  - P = exp2(S) (fixed-max softmax; exp2-domain scores max ~8 << 127)
//  - PV: v_mfma_f32_16x16x16_f16 — its B layout [k=quad*4+i][n=l15] EQUALS
//    the C/D layout, so P chains from accumulator to PV operand IN REGISTERS
//    (no LDS round-trip, no shuffles).  V^T is the f16 A-operand (8B loads).
// No barriers; equal-length waves via pair (p, 127-p); kv-striped by S.
// grid 64*S blocks (1-D), 4 waves; b=(bid&7)>>1 XCD-local; 4 blocks/CU.
// Partials: Opart[(b*128+qt32)*S+s] bf16 [32 qrow][64 a]; ml l per row.
// ---------------------------------------------------------------------------
__global__ __launch_bounds__(256, 4) void flash_kernel(
    const unsigned short* __restrict__ qg, const unsigned short* __restrict__ kg,
    const unsigned short* __restrict__ v_t,
    unsigned short* __restrict__ Opart, float* __restrict__ ml,
    int S, int lgS)
{
    const int bid  = blockIdx.x;
    const int tid  = threadIdx.x;
    const int wave = tid >> 6, lane = tid & 63, quad = lane >> 4, l15 = lane & 15;
    const int b    = (bid & 7) >> 1;                  // XCD-pair-local batch
    const int idx  = (bid >> 3) * 2 + (bid & 1);      // 0..(16*S-1)
    const int u    = idx * 4 + wave;                  // 0..(64*S-1)
    const int p    = u >> lgS;                        // 0..63 (pair index)
    const int s    = u & (S - 1);                     // stripe

    __shared__ unsigned short lds[4 * 32 * PLS];      // epilogue-only scratch
    unsigned short* tw = lds + wave * (32 * PLS);

    const unsigned short* kb0 = kg  + ((size_t)b << 12) * An;
    const unsigned short* vb0 = v_t + (size_t)b * An * Tn;

#pragma unroll 1
    for (int tile = 0; tile < 2; tile++) {
        const int qt32  = tile ? (127 - p) : p;       // 32-row tile index
        const int qrow0 = qt32 * 32;
        const int tmax  = qt32 >> 1;

        // Q B-fragments (QK): B[k=a][n=qrow], g = qrow group (16 rows)
        short8 qB[2][2];
        {
            const unsigned short* qb = qg + (((size_t)b << 12) + qrow0) * An;
#pragma unroll
            for (int g = 0; g < 2; g++)
#pragma unroll
                for (int c = 0; c < 2; c++)
                    qB[g][c] = *(const short8*)(qb + (size_t)(16 * g + l15) * An + c * 32 + quad * 8);
        }

        float l_lane[2] = {0.f, 0.f};
        f32x4 O[4][2];    // O^T[a=nt*16+quad*4+rg][qrow=16g+l15]
#pragma unroll
        for (int nt = 0; nt < 4; nt++)
#pragma unroll
            for (int g = 0; g < 2; g++) O[nt][g] = (f32x4){0.f, 0.f, 0.f, 0.f};

#pragma unroll 1
        for (int t = s; t <= tmax; t += S) {
            // K A-fragments: A[m=kv=nt*16+l15][k=a]
            short8 KA[4][2];
            {
                const unsigned short* kb = kb0 + (size_t)t * (64 * An);
#pragma unroll
                for (int nt = 0; nt < 4; nt++)
#pragma unroll
                    for (int c = 0; c < 2; c++)
                        KA[nt][c] = *(const short8*)(kb + (nt * 16 + l15) * An + c * 32 + quad * 8);
            }

            // S^T = K Q^T : 16 MFMA K=32.  St[kc][g] rows kv=kc*16+quad*4+rg
            f32x4 St[4][2];
#pragma unroll
            for (int nt = 0; nt < 4; nt++)
#pragma unroll
                for (int g = 0; g < 2; g++) {
                    f32x4 a0 = (f32x4){0.f, 0.f, 0.f, 0.f};
                    a0 = mfma16(KA[nt][0], qB[g][0], a0);
                    a0 = mfma16(KA[nt][1], qB[g][1], a0);
                    St[nt][g] = a0;
                }

            // V^T A-fragments (f16, 8B each) — issued here to cover exp2
            // VA[nt_a][kc]: lane a=nt_a*16+l15, kv=kc*16+quad*4+i
            f16x4 VA[4][4];
            {
                const unsigned short* vb = vb0 + (size_t)t * 64 + quad * 4;
#pragma unroll
                for (int nt = 0; nt < 4; nt++)
#pragma unroll
                    for (int kc = 0; kc < 4; kc++)
                        VA[nt][kc] = *(const f16x4*)(vb + (size_t)(nt * 16 + l15) * Tn + kc * 16);
            }

            // causal mask on the diagonal tile
            if (t == tmax) {
                const int kvb = t * 64 + quad * 4;
#pragma unroll
                for (int nt = 0; nt < 4; nt++)
#pragma unroll
                    for (int g = 0; g < 2; g++) {
                        const int qr = qrow0 + 16 * g + l15;
#pragma unroll
                        for (int rg = 0; rg < 4; rg++)
                            if (kvb + nt * 16 + rg > qr) St[nt][g][rg] = -__builtin_inff();
                    }
            }

            // P = exp2(S); per-lane l accumulation (no cross-lane ops)
#pragma unroll
            for (int g = 0; g < 2; g++) {
                float rs = l_lane[g];
#pragma unroll
                for (int nt = 0; nt < 4; nt++)
#pragma unroll
                    for (int rg = 0; rg < 4; rg++) {
                        const float pv = exp2f(St[nt][g][rg]);
                        St[nt][g][rg] = pv;
                        rs += pv;
                    }
                l_lane[g] = rs;
            }

            // PV: O^T += V^T P^T, 32 MFMA K=16; P chains in registers
#pragma unroll
            for (int kc = 0; kc < 4; kc++)
#pragma unroll
                for (int g = 0; g < 2; g++) {
                    const f16x4 pb = { (_Float16)St[kc][g][0], (_Float16)St[kc][g][1],
                                       (_Float16)St[kc][g][2], (_Float16)St[kc][g][3] };
#pragma unroll
                    for (int nt = 0; nt < 4; nt++)
                        O[nt][g] = mfma16h(VA[nt][kc], pb, O[nt][g]);
                }
        }

        // ---- epilogue: reduce l across quads; O^T -> [qrow][a]; store ----
        float l_red[2];
#pragma unroll
        for (int g = 0; g < 2; g++) {
            float rs = l_lane[g];
            rs += __shfl_xor(rs, 16);
            rs += __shfl_xor(rs, 32);
            l_red[g] = rs;
        }
#pragma unroll
        for (int nt = 0; nt < 4; nt++)
#pragma unroll
            for (int g = 0; g < 2; g++) {
                const unsigned int d0 = packbf2(O[nt][g][0], O[nt][g][1]);
                const unsigned int d1 = packbf2(O[nt][g][2], O[nt][g][3]);
                *(short4v*)&tw[(16 * g + l15) * PLS + 16 * nt + quad * 4] =
                    __builtin_bit_cast(short4v, (uint2v){d0, d1});
            }
        {
            const size_t unit = (size_t)(b * 128 + qt32) * (size_t)S + s;
            unsigned short* ob = Opart + unit * 2048;
            const int row = lane >> 1;
#pragma unroll
            for (int pp = 0; pp < 4; pp++) {
                const int colh = (lane & 1) * 8 + pp * 16;
                *(short8*)(ob + row * 64 + colh) = *(const short8*)&tw[row * PLS + colh];
            }
            if (quad == 0) {
                float* mlb = ml + unit * 32;
#pragma unroll
                for (int g = 0; g < 2; g++)
                    mlb[16 * g + l15] = l_red[g];
            }
        }
    }
}

// ---------------------------------------------------------------------------
// Kernel 3: merge the S kv-stripe partials (unweighted — fixed-max softmax)
// -> out fp32 [b][t][a].  grid (128, 4).  Thread: qr=tid>>3, a8=(tid&7)*8.
// ---------------------------------------------------------------------------
__global__ __launch_bounds__(256) void merge_kernel(
    const unsigned short* __restrict__ Opart, const float* __restrict__ ml,
    float* __restrict__ out, int S)
{
    const int qt32 = blockIdx.x, b = blockIdx.y;
    const int tid = threadIdx.x;
    const int qr  = tid >> 3;            // 0..31
    const int a8  = (tid & 7) * 8;
    const size_t ub = (size_t)(b * 128 + qt32) * (size_t)S;

    float acc[8];
#pragma unroll
    for (int x = 0; x < 8; x++) acc[x] = 0.f;
    float lsum = 0.f;

#pragma unroll 1
    for (int s = 0; s < S; s++) {
        lsum += ml[(ub + s) * 32 + qr];
        const short8 ov = *(const short8*)&Opart[(ub + s) * 2048 + qr * 64 + a8];
#pragma unroll
        for (int x = 0; x < 8; x++) acc[x] += bf2f((unsigned short)ov[x]);
    }
    const float inv = 1.f / lsum;
    float* o = out + (((size_t)b << 12) + qt32 * 32 + qr) * An + a8;
    float4 r0 = {acc[0] * inv, acc[1] * inv, acc[2] * inv, acc[3] * inv};
    float4 r1 = {acc[4] * inv, acc[5] * inv, acc[6] * inv, acc[7] * inv};
    *(float4*)o       = r0;
    *(float4*)(o + 4) = r1;
}

// ---------------------------------------------------------------------------
extern "C" void kernel_launch(void* const* d_in, const int* in_sizes, int n_in,
                              void* d_out, int out_size, void* d_ws, size_t ws_size,
                              hipStream_t stream) {
    const float* emb = (const float*)d_in[0];
    const float* Wk  = (const float*)d_in[1];
    const float* bk  = (const float*)d_in[2];
    const float* Wq  = (const float*)d_in[3];
    const float* bq  = (const float*)d_in[4];
    const float* Wv  = (const float*)d_in[5];
    const float* bv  = (const float*)d_in[6];
    float* out = (float*)d_out;

    char* ws = (char*)d_ws;
    const size_t MB = 1024 * 1024;

    // stripe count: prefer 16 -> 1024 blocks = 4 blocks/CU, 16 waves/CU
    int S = 8, lgS = 3;
    {
        const size_t need16 = 6 * MB + 64 * 1024
                            + (size_t)512 * 16 * 128        // ml: 8192 units * 128 B
                            + (size_t)512 * 16 * 4096;      // Opart: 8192 units * 4 KB
        if (need16 <= ws_size) { S = 16; lgS = 4; }
    }

    unsigned short* q     = (unsigned short*)(ws);                        // 2 MB
    unsigned short* k     = (unsigned short*)(ws + 2 * MB);               // 2 MB
    unsigned short* v_t   = (unsigned short*)(ws + 4 * MB);               // 2 MB (f16)
    float*          ml    = (float*)(ws + 6 * MB + 64 * 1024);            // 512*S*128 B
    unsigned short* Opart = (unsigned short*)(ws + 6 * MB + 64 * 1024 + (size_t)512 * S * 128);

    proj_kernel<<<512, 256, 0, stream>>>(emb, Wq, Wk, Wv, bq, bk, bv, q, k, v_t);
    flash_kernel<<<64 * S, 256, 0, stream>>>(q, k, v_t, Opart, ml, S, lgS);
    merge_kernel<<<dim3(128, 4), 256, 0, stream>>>(Opart, ml, out, S);
}

// Round 12
// 144.491 us; speedup vs baseline: 1.1833x; 1.1833x over previous
//
#include <hip/hip_runtime.h>
#include <math.h>

#define Bn 4
#define Tn 4096
#define En 256
#define An 64
#define SS 32     // kv stripes per q-tile (8 stripe-groups x 4 waves)
#define PLS 72    // P/O LDS row stride in shorts (144 B, 16B-aligned)
#define WLS 264   // W LDS row stride in shorts (528 B, 16B-aligned)

typedef __attribute__((ext_vector_type(8))) short short8;
typedef __attribute__((ext_vector_type(8))) __bf16 bf16x8;
typedef __attribute__((ext_vector_type(4))) float f32x4;
typedef __attribute__((ext_vector_type(4))) short short4v;
typedef __attribute__((ext_vector_type(2))) unsigned int uint2v;

__device__ __forceinline__ f32x4 mfma16(short8 a, short8 b, f32x4 c) {
    return __builtin_amdgcn_mfma_f32_16x16x32_bf16(
        __builtin_bit_cast(bf16x8, a), __builtin_bit_cast(bf16x8, b), c, 0, 0, 0);
}
__device__ __forceinline__ unsigned short f2bf(float x) {   // RNE fp32->bf16
    unsigned int u = __builtin_bit_cast(unsigned int, x);
    u += 0x7fffu + ((u >> 16) & 1u);
    return (unsigned short)(u >> 16);
}
__device__ __forceinline__ float bf2f(unsigned short h) {
    return __builtin_bit_cast(float, (unsigned int)h << 16);
}
__device__ __forceinline__ unsigned int packbf2(float lo, float hi) {
    return (unsigned int)f2bf(lo) | ((unsigned int)f2bf(hi) << 16);
}

// ---------------------------------------------------------------------------
// Kernel 1: QKV projection, in-kernel W staging, LDS-transposed coalesced
// stores (R10 version — known good).  grid 512: jh=bid&1, rb=bid>>1.
// Outputs: q bf16 [b][t][a] pre-scaled 0.125*log2e, k bf16 [b][t][a],
//          v_t bf16 [b][a][t].
// ---------------------------------------------------------------------------
__global__ __launch_bounds__(256, 2) void proj_kernel(
    const float* __restrict__ emb,
    const float* __restrict__ Wq, const float* __restrict__ Wk, const float* __restrict__ Wv,
    const float* __restrict__ bq, const float* __restrict__ bk, const float* __restrict__ bv,
    unsigned short* __restrict__ qg, unsigned short* __restrict__ kg,
    unsigned short* __restrict__ v_t)
{
    const int bid  = blockIdx.x;
    const int tid  = threadIdx.x;
    const int wave = tid >> 6, lane = tid & 63, quad = lane >> 4, l15 = lane & 15;
    const int jh   = bid & 1;
    const int rb   = bid >> 1;
    const int row0  = rb * 64;
    const int b     = row0 >> 12;
    const int trow0 = row0 & 4095;

    __shared__ unsigned short Wl[96 * WLS];
    __shared__ unsigned short vtr[64 * PLS];

    {   // stage 96 W columns, transposed+bf16
        const float* __restrict__ srcA = jh ? Wv : Wq;
        const int lrbA = jh ? 32 : 0;
#pragma unroll
        for (int it = 0; it < 16; it++) {
            const int idx = it * 256 + tid;
            const int e   = idx >> 4;
            const int c4  = (idx & 15) * 4;
            float4 w = *(const float4*)&srcA[(size_t)e * An + c4];
            Wl[(lrbA + c4 + 0) * WLS + e] = f2bf(w.x);
            Wl[(lrbA + c4 + 1) * WLS + e] = f2bf(w.y);
            Wl[(lrbA + c4 + 2) * WLS + e] = f2bf(w.z);
            Wl[(lrbA + c4 + 3) * WLS + e] = f2bf(w.w);
        }
        const int coloff = jh ? 32 : 0;
        const int lrbB   = jh ? 0 : 64;
#pragma unroll
        for (int it = 0; it < 8; it++) {
            const int idx = it * 256 + tid;
            const int e   = idx >> 3;
            const int c4  = (idx & 7) * 4;
            float4 w = *(const float4*)&Wk[(size_t)e * An + coloff + c4];
            Wl[(lrbB + c4 + 0) * WLS + e] = f2bf(w.x);
            Wl[(lrbB + c4 + 1) * WLS + e] = f2bf(w.y);
            Wl[(lrbB + c4 + 2) * WLS + e] = f2bf(w.z);
            Wl[(lrbB + c4 + 3) * WLS + e] = f2bf(w.w);
        }
    }

    short8 A[8];
    {
        const float* erow = emb + (size_t)(row0 + wave * 16 + l15) * En;
#pragma unroll
        for (int c = 0; c < 8; c++) {
            const float* pp = erow + c * 32 + quad * 8;
            float4 f0 = *(const float4*)pp;
            float4 f1 = *(const float4*)(pp + 4);
            A[c] = (short8){(short)f2bf(f0.x), (short)f2bf(f0.y), (short)f2bf(f0.z), (short)f2bf(f0.w),
                            (short)f2bf(f1.x), (short)f2bf(f1.y), (short)f2bf(f1.z), (short)f2bf(f1.w)};
        }
    }
    __syncthreads();

    f32x4 acc[6];
#pragma unroll
    for (int x = 0; x < 6; x++) acc[x] = (f32x4){0.f, 0.f, 0.f, 0.f};

#pragma unroll
    for (int x = 0; x < 6; x++) {
        const unsigned short* wrow = &Wl[(x * 16 + l15) * WLS];
#pragma unroll
        for (int c = 0; c < 8; c++)
            acc[x] = mfma16(A[c], *(const short8*)(wrow + c * 32 + quad * 8), acc[x]);
    }

    const float QS = 0.125f * 1.4426950408889634f;
    const int row_l = wave * 16 + quad * 4;

    if (jh == 0) {
        __syncthreads();
#pragma unroll
        for (int x = 0; x < 4; x++) {
            const int al = x * 16 + l15;
            const float bsv = bq[al];
#pragma unroll
            for (int rg = 0; rg < 4; rg++)
                vtr[(row_l + rg) * PLS + al] = f2bf((acc[x][rg] + bsv) * QS);
        }
        __syncthreads();
        if (tid < 128) {
            const int row = tid >> 1, cg = (tid & 1) * 32;
            unsigned short* dst = qg + (size_t)(row0 + row) * An + cg;
            *(short8*)dst        = *(const short8*)&vtr[row * PLS + cg];
            *(short8*)(dst + 8)  = *(const short8*)&vtr[row * PLS + cg + 8];
            *(short8*)(dst + 16) = *(const short8*)&vtr[row * PLS + cg + 16];
            *(short8*)(dst + 24) = *(const short8*)&vtr[row * PLS + cg + 24];
        }
        __syncthreads();
#pragma unroll
        for (int x = 4; x < 6; x++) {
            const int al = (x - 4) * 16 + l15;
            const float bsv = bk[al];
#pragma unroll
            for (int rg = 0; rg < 4; rg++)
                vtr[(row_l + rg) * PLS + al] = f2bf(acc[x][rg] + bsv);
        }
        __syncthreads();
        if (tid < 64) {
            const int row = tid;
            unsigned short* dst = kg + (size_t)(row0 + row) * An;
            *(short8*)dst        = *(const short8*)&vtr[row * PLS];
            *(short8*)(dst + 8)  = *(const short8*)&vtr[row * PLS + 8];
            *(short8*)(dst + 16) = *(const short8*)&vtr[row * PLS + 16];
            *(short8*)(dst + 24) = *(const short8*)&vtr[row * PLS + 24];
        }
    } else {
        __syncthreads();
#pragma unroll
        for (int x = 0; x < 2; x++) {
            const int al = (2 + x) * 16 + l15;
            const float bsv = bk[al];
#pragma unroll
            for (int rg = 0; rg < 4; rg++)
                vtr[(row_l + rg) * PLS + al] = f2bf(acc[x][rg] + bsv);
        }
        __syncthreads();
        if (tid < 64) {
            const int row = tid;
            unsigned short* dst = kg + (size_t)(row0 + row) * An + 32;
            *(short8*)dst        = *(const short8*)&vtr[row * PLS + 32];
            *(short8*)(dst + 8)  = *(const short8*)&vtr[row * PLS + 40];
            *(short8*)(dst + 16) = *(const short8*)&vtr[row * PLS + 48];
            *(short8*)(dst + 24) = *(const short8*)&vtr[row * PLS + 56];
        }
        __syncthreads();
#pragma unroll
        for (int x = 2; x < 6; x++) {
            const int al = (x - 2) * 16 + l15;
            const float bsv = bv[al];
#pragma unroll
            for (int rg = 0; rg < 4; rg++)
                vtr[al * PLS + row_l + rg] = f2bf(acc[x][rg] + bsv);
        }
        __syncthreads();
        {
            const int a  = tid >> 2;
            const int tg = (tid & 3) * 16;
            unsigned short* dst = v_t + (size_t)(b * 64 + a) * Tn + trow0 + tg;
            *(short8*)dst       = *(const short8*)&vtr[a * PLS + tg];
            *(short8*)(dst + 8) = *(const short8*)&vtr[a * PLS + tg + 8];
        }
    }
}

// ---------------------------------------------------------------------------
// Kernel 2: flash attention — R9's 64-row-per-wave kernel (best measured) with
// S=32 stripes -> 1024 blocks = 4 blocks/CU (VGPR<=128 allows 4 waves/SIMD),
// plus an IN-BLOCK merge: a block's 4 waves are 4 adjacent stripes of the
// same tile pair, merged through the existing LDS slices -> one Opart unit.
// grid (256, 4): bx -> p = (bx*4+wave)>>5 pair index, stripe sid=(bx&7)*4+wave.
// Units per tile: 8 (stripe-groups).  Opart[(b*64+qt)*8 + jj] bf16 [64][64];
// ml[unit*128 + {0..63 m', 64..127 l'}].
// ---------------------------------------------------------------------------
__global__ __launch_bounds__(256, 2) void flash_kernel(
    const unsigned short* __restrict__ qg, const unsigned short* __restrict__ kg,
    const unsigned short* __restrict__ v_t,
    unsigned short* __restrict__ Opart, float* __restrict__ ml)
{
    const int b    = blockIdx.y;
    const int tid  = threadIdx.x;
    const int wave = tid >> 6, lane = tid & 63, quad = lane >> 4, l15 = lane & 15;
    const int bx   = blockIdx.x;
    const int p    = bx >> 3;             // pair index 0..31
    const int jj   = bx & 7;              // stripe-group 0..7
    const int sid  = jj * 4 + wave;       // stripe 0..31

    __shared__ unsigned short lds[4 * 64 * PLS];   // per-wave P/O slices
    __shared__ float mlds[4][2][64];               // per-wave m,l per row
    unsigned short* tw = lds + wave * (64 * PLS);

    const unsigned short* kb0 = kg  + ((size_t)b << 12) * An;
    const unsigned short* vb0 = v_t + (size_t)b * An * Tn;

#pragma unroll 1
    for (int tile = 0; tile < 2; tile++) {
        const int qt    = tile ? (63 - p) : p;   // 64-row tile index
        const int qrow0 = qt * 64;
        const int tmax  = qt;

        // Q B-fragments: B[k=a][n=qrow], group g = qrows 16g..16g+15
        short8 qB[4][2];
        {
            const unsigned short* qb = qg + (((size_t)b << 12) + qrow0) * An;
#pragma unroll
            for (int g = 0; g < 4; g++)
#pragma unroll
                for (int c = 0; c < 2; c++)
                    qB[g][c] = *(const short8*)(qb + (size_t)(16 * g + l15) * An + c * 32 + quad * 8);
        }

        float m_s[4] = {-__builtin_inff(), -__builtin_inff(), -__builtin_inff(), -__builtin_inff()};
        float l_s[4] = {0.f, 0.f, 0.f, 0.f};
        f32x4 O[4][4];
#pragma unroll
        for (int nt = 0; nt < 4; nt++)
#pragma unroll
            for (int g = 0; g < 4; g++) O[nt][g] = (f32x4){0.f, 0.f, 0.f, 0.f};

        int t = sid;
        if (t <= tmax) {
            short8 KA[4][2];
            {
                const unsigned short* kb = kb0 + (size_t)t * (64 * An);
#pragma unroll
                for (int nt = 0; nt < 4; nt++)
#pragma unroll
                    for (int c = 0; c < 2; c++)
                        KA[nt][c] = *(const short8*)(kb + (nt * 16 + l15) * An + c * 32 + quad * 8);
            }
            for (;;) {
                // V^T fragments for t
                short8 VA[4][2];
                {
                    const unsigned short* vb = vb0 + (size_t)t * 64;
#pragma unroll
                    for (int nt = 0; nt < 4; nt++)
#pragma unroll
                        for (int c = 0; c < 2; c++)
                            VA[nt][c] = *(const short8*)(vb + (size_t)(nt * 16 + l15) * Tn + c * 32 + quad * 8);
                }

                // prefetch next K tile
                const int tn = t + SS;
                const bool more = (tn <= tmax);
                short8 KN[4][2];
                if (more) {
                    const unsigned short* kb = kb0 + (size_t)tn * (64 * An);
#pragma unroll
                    for (int nt = 0; nt < 4; nt++)
#pragma unroll
                        for (int c = 0; c < 2; c++)
                            KN[nt][c] = *(const short8*)(kb + (nt * 16 + l15) * An + c * 32 + quad * 8);
                }

                const bool diag = (t == tmax);

                // per q-column group: S^T slab, softmax, P->LDS, PV
#pragma unroll
                for (int g = 0; g < 4; g++) {
                    f32x4 St[4];
#pragma unroll
                    for (int nt = 0; nt < 4; nt++) {
                        f32x4 a0 = (f32x4){0.f, 0.f, 0.f, 0.f};
                        a0 = mfma16(KA[nt][0], qB[g][0], a0);
                        a0 = mfma16(KA[nt][1], qB[g][1], a0);
                        St[nt] = a0;
                    }
                    if (diag) {
                        const int qr = 16 * g + l15;
                        const int kvb = quad * 4;
#pragma unroll
                        for (int nt = 0; nt < 4; nt++)
#pragma unroll
                            for (int rg = 0; rg < 4; rg++)
                                if (nt * 16 + kvb + rg > qr) St[nt][rg] = -__builtin_inff();
                    }
                    float mt = -__builtin_inff();
#pragma unroll
                    for (int nt = 0; nt < 4; nt++)
                        mt = fmaxf(mt, fmaxf(fmaxf(St[nt][0], St[nt][1]),
                                             fmaxf(St[nt][2], St[nt][3])));
                    mt = fmaxf(mt, __shfl_xor(mt, 16));
                    mt = fmaxf(mt, __shfl_xor(mt, 32));
                    const float mn = fmaxf(m_s[g], mt);
                    const float alpha = exp2f(m_s[g] - mn);
                    m_s[g] = mn;
                    float rs = 0.f;
#pragma unroll
                    for (int nt = 0; nt < 4; nt++) {
#pragma unroll
                        for (int rg = 0; rg < 4; rg++) {
                            const float pv = exp2f(St[nt][rg] - mn);
                            St[nt][rg] = pv;
                            rs += pv;
                        }
                        const unsigned int d0 = packbf2(St[nt][0], St[nt][1]);
                        const unsigned int d1 = packbf2(St[nt][2], St[nt][3]);
                        *(short4v*)&tw[(16 * g + l15) * PLS + 16 * nt + quad * 4] =
                            __builtin_bit_cast(short4v, (uint2v){d0, d1});
                    }
                    rs += __shfl_xor(rs, 16);
                    rs += __shfl_xor(rs, 32);
                    l_s[g] = l_s[g] * alpha + rs;
                    if (!__all(alpha == 1.f)) {
#pragma unroll
                        for (int nt = 0; nt < 4; nt++)
#pragma unroll
                            for (int rg = 0; rg < 4; rg++) O[nt][g][rg] *= alpha;
                    }
#pragma unroll
                    for (int c = 0; c < 2; c++) {
                        const short8 pb = *(const short8*)&tw[(16 * g + l15) * PLS + c * 32 + quad * 8];
#pragma unroll
                        for (int nt = 0; nt < 4; nt++)
                            O[nt][g] = mfma16(VA[nt][c], pb, O[nt][g]);
                    }
                }

                if (!more) break;
                t = tn;
#pragma unroll
                for (int nt = 0; nt < 4; nt++)
#pragma unroll
                    for (int c = 0; c < 2; c++) KA[nt][c] = KN[nt][c];
            }
        }

        // ---- per-wave epilogue: O^T -> [qrow][a] in own LDS slice; m,l ----
#pragma unroll
        for (int nt = 0; nt < 4; nt++)
#pragma unroll
            for (int g = 0; g < 4; g++) {
                const unsigned int d0 = packbf2(O[nt][g][0], O[nt][g][1]);
                const unsigned int d1 = packbf2(O[nt][g][2], O[nt][g][3]);
                *(short4v*)&tw[(16 * g + l15) * PLS + 16 * nt + quad * 4] =
                    __builtin_bit_cast(short4v, (uint2v){d0, d1});
            }
        if (quad == 0) {
#pragma unroll
            for (int g = 0; g < 4; g++) {
                mlds[wave][0][16 * g + l15] = m_s[g];
                mlds[wave][1][16 * g + l15] = l_s[g];
            }
        }
        __syncthreads();

        // ---- in-block merge of the 4 wave-stripes -> one Opart unit ----
        {
            const int r   = tid >> 2;            // 0..63
            const int c16 = (tid & 3) * 16;
            float mw[4], lw[4];
#pragma unroll
            for (int w = 0; w < 4; w++) { mw[w] = mlds[w][0][r]; lw[w] = mlds[w][1][r]; }
            const float mstar = fmaxf(fmaxf(mw[0], mw[1]), fmaxf(mw[2], mw[3]));
            float acc[16];
#pragma unroll
            for (int x = 0; x < 16; x++) acc[x] = 0.f;
            float lsum = 0.f;
#pragma unroll
            for (int w = 0; w < 4; w++) {
                const float wsf = (mw[w] == -__builtin_inff()) ? 0.f : exp2f(mw[w] - mstar);
                lsum += lw[w] * wsf;
                if (wsf != 0.f) {
                    const unsigned short* tp = &lds[w * 64 * PLS + r * PLS + c16];
                    const short8 o0 = *(const short8*)tp;
                    const short8 o1 = *(const short8*)(tp + 8);
#pragma unroll
                    for (int x = 0; x < 8; x++) {
                        acc[x]     += wsf * bf2f((unsigned short)o0[x]);
                        acc[8 + x] += wsf * bf2f((unsigned short)o1[x]);
                    }
                }
            }
            const size_t unit = (size_t)(b * 64 + qt) * 8 + jj;
            unsigned short* ob = Opart + unit * 4096 + r * 64 + c16;
            short4v s0 = __builtin_bit_cast(short4v,
                (uint2v){packbf2(acc[0], acc[1]), packbf2(acc[2], acc[3])});
            short4v s1 = __builtin_bit_cast(short4v,
                (uint2v){packbf2(acc[4], acc[5]), packbf2(acc[6], acc[7])});
            short4v s2 = __builtin_bit_cast(short4v,
                (uint2v){packbf2(acc[8], acc[9]), packbf2(acc[10], acc[11])});
            short4v s3 = __builtin_bit_cast(short4v,
                (uint2v){packbf2(acc[12], acc[13]), packbf2(acc[14], acc[15])});
            *(short4v*)ob       = s0;
            *(short4v*)(ob + 4) = s1;
            *(short4v*)(ob + 8) = s2;
            *(short4v*)(ob + 12) = s3;
            if ((tid & 3) == 0) {
                ml[unit * 128 + r]      = mstar;
                ml[unit * 128 + 64 + r] = lsum;
            }
        }
        __syncthreads();   // protect LDS slices before tile 2 reuses them
    }
}

// ---------------------------------------------------------------------------
// Kernel 3: merge the 8 stripe-group units per tile -> out fp32 [b][t][a].
// grid (64, 4).  Thread: r = tid>>2 (0..63), c16 = (tid&3)*16.
// ---------------------------------------------------------------------------
__global__ __launch_bounds__(256) void merge_kernel(
    const unsigned short* __restrict__ Opart, const float* __restrict__ ml,
    float* __restrict__ out)
{
    const int qt = blockIdx.x, b = blockIdx.y;
    const int tid = threadIdx.x;
    const int r   = tid >> 2;
    const int c16 = (tid & 3) * 16;
    const size_t ub = (size_t)(b * 64 + qt) * 8;

    float mw[8], lw[8];
#pragma unroll
    for (int j = 0; j < 8; j++) {
        mw[j] = ml[(ub + j) * 128 + r];
        lw[j] = ml[(ub + j) * 128 + 64 + r];
    }
    float mstar = -__builtin_inff();
#pragma unroll
    for (int j = 0; j < 8; j++) mstar = fmaxf(mstar, mw[j]);

    float acc[16];
#pragma unroll
    for (int x = 0; x < 16; x++) acc[x] = 0.f;
    float lsum = 0.f;

#pragma unroll 1
    for (int j = 0; j < 8; j++) {
        const float wsf = (mw[j] == -__builtin_inff()) ? 0.f : exp2f(mw[j] - mstar);
        lsum += lw[j] * wsf;
        if (wsf != 0.f) {
            const unsigned short* op = &Opart[(ub + j) * 4096 + r * 64 + c16];
            const short8 o0 = *(const short8*)op;
            const short8 o1 = *(const short8*)(op + 8);
#pragma unroll
            for (int x = 0; x < 8; x++) {
                acc[x]     += wsf * bf2f((unsigned short)o0[x]);
                acc[8 + x] += wsf * bf2f((unsigned short)o1[x]);
            }
        }
    }
    const float inv = 1.f / lsum;
    float* o = out + (((size_t)b << 12) + qt * 64 + r) * An + c16;
#pragma unroll
    for (int h = 0; h < 4; h++) {
        float4 rr = {acc[h * 4] * inv, acc[h * 4 + 1] * inv,
                     acc[h * 4 + 2] * inv, acc[h * 4 + 3] * inv};
        *(float4*)(o + h * 4) = rr;
    }
}

// ---------------------------------------------------------------------------
extern "C" void kernel_launch(void* const* d_in, const int* in_sizes, int n_in,
                              void* d_out, int out_size, void* d_ws, size_t ws_size,
                              hipStream_t stream) {
    const float* emb = (const float*)d_in[0];
    const float* Wk  = (const float*)d_in[1];
    const float* bk  = (const float*)d_in[2];
    const float* Wq  = (const float*)d_in[3];
    const float* bq  = (const float*)d_in[4];
    const float* Wv  = (const float*)d_in[5];
    const float* bv  = (const float*)d_in[6];
    float* out = (float*)d_out;

    char* ws = (char*)d_ws;
    const size_t MB = 1024 * 1024;
    // layout: q 2MB | k 2MB | v_t 2MB | ml 1MB (2048 units * 512 B) | Opart 16MB
    unsigned short* q     = (unsigned short*)(ws);
    unsigned short* k     = (unsigned short*)(ws + 2 * MB);
    unsigned short* v_t   = (unsigned short*)(ws + 4 * MB);
    float*          ml    = (float*)(ws + 6 * MB);
    unsigned short* Opart = (unsigned short*)(ws + 7 * MB);

    proj_kernel<<<512, 256, 0, stream>>>(emb, Wq, Wk, Wv, bq, bk, bv, q, k, v_t);
    flash_kernel<<<dim3(256, 4), 256, 0, stream>>>(q, k, v_t, Opart, ml);
    merge_kernel<<<dim3(64, 4), 256, 0, stream>>>(Opart, ml, out);
}